// Round 10
// baseline (247.075 us; speedup 1.0000x reference)
//
#include <hip/hip_runtime.h>
#include <hip/hip_bf16.h>
#include <math.h>

// Problem constants
#define BATCH   8
#define LSEQ    4096      // 64*64
#define CMODEL  128
#define DIN     256
#define NSTATE  16
#define RRANK   8
#define NCH     256       // chunks per sequence
#define TCH     16        // timesteps per chunk (NCH*TCH == LSEQ)

typedef __attribute__((ext_vector_type(8))) short short8;
typedef __attribute__((ext_vector_type(4))) float f32x4;
typedef __attribute__((ext_vector_type(2))) float f32x2;

__device__ __forceinline__ float sigmoid_fast(float x) {
    return __builtin_amdgcn_rcpf(1.0f + __expf(-x));
}
__device__ __forceinline__ float silu_fast(float x) { return x * sigmoid_fast(x); }
__device__ __forceinline__ float softplus_fast(float x) {
    return fmaxf(x, 0.0f) + __logf(1.0f + __expf(-fabsf(x)));
}
__device__ __forceinline__ unsigned short f2bf(float f) {
    unsigned u = __float_as_uint(f);
    return (unsigned short)((u + 0x7FFFu + ((u >> 16) & 1u)) >> 16);   // RNE
}
__device__ __forceinline__ float bf2f(unsigned short u) {
    return __uint_as_float(((unsigned)u) << 16);
}
// packed fp32x2 -> bf16x2 (v_cvt_pk_bf16_f32 on gfx950); a -> low, b -> high
__device__ __forceinline__ unsigned pk2bf(float a, float b) {
    __hip_bfloat162 t = __float22bfloat162_rn(make_float2(a, b));
    unsigned r;
    __builtin_memcpy(&r, &t, 4);
    return r;
}

// dA[n] = exp(dtv*A[n]); A[n] == (n+1)*A[0] fast path: 1 exp + mul chain.
__device__ __forceinline__ void dA_powers(float dtv, const float* A, bool fast,
                                          float* dA)
{
    if (fast) {
        float e1 = __expf(dtv * A[0]);
        float e2 = e1 * e1;
        float e4 = e2 * e2;
        float e8 = e4 * e4;
        dA[0] = e1;        dA[1] = e2;        dA[2] = e2 * e1;   dA[3] = e4;
        dA[4] = e4 * e1;   dA[5] = e4 * e2;   dA[6] = e4 * dA[2]; dA[7] = e8;
        dA[8] = e8 * e1;   dA[9] = e8 * e2;   dA[10] = e8 * dA[2]; dA[11] = e8 * e4;
        dA[12] = e8 * dA[4]; dA[13] = e8 * dA[5]; dA[14] = e8 * dA[6]; dA[15] = e8 * e8;
    } else {
        #pragma unroll
        for (int n = 0; n < 16; ++n) dA[n] = __expf(dtv * A[n]);
    }
}

#define LSTR 72   // LDS row stride (bf16 units): 64 data + 8 pad; 2-way max = free

// ---------------------------------------------------------------------------
// K0: weight transposes (tiny) + part zero. grid 25, block 256
// ---------------------------------------------------------------------------
__device__ __forceinline__ void tr64_bf(const float* __restrict__ src, int lds,
                                        int r0, int c0,
                                        unsigned short* __restrict__ dst, int ldd)
{
    __shared__ float ts[64][65];
    const int tid = threadIdx.x;
    #pragma unroll
    for (int it = 0; it < 4; ++it) {
        int slot = tid + it * 256;
        int i = slot >> 4, j4 = slot & 15;
        float4 v = *(const float4*)&src[(size_t)(r0 + i) * lds + c0 + j4 * 4];
        ts[i][j4*4+0] = v.x; ts[i][j4*4+1] = v.y;
        ts[i][j4*4+2] = v.z; ts[i][j4*4+3] = v.w;
    }
    __syncthreads();
    #pragma unroll
    for (int it = 0; it < 4; ++it) {
        int slot = tid + it * 256;
        int row = slot >> 4, c4 = slot & 15;
        unsigned p0 = pk2bf(ts[c4*4+0][row], ts[c4*4+1][row]);
        unsigned p1 = pk2bf(ts[c4*4+2][row], ts[c4*4+3][row]);
        unsigned long long u = (unsigned long long)p0 | ((unsigned long long)p1 << 32);
        *(unsigned long long*)&dst[(size_t)(c0 + row) * ldd + r0 + c4 * 4] = u;
    }
}

__global__ __launch_bounds__(256) void k0_setup(
    const float* __restrict__ W_in, const float* __restrict__ W_out,
    unsigned short* __restrict__ wtin, unsigned short* __restrict__ wtout,
    float* __restrict__ part)
{
    const int bid = blockIdx.x;
    if (bid < 16) {
        int ct = bid >> 3, jt = bid & 7;
        tr64_bf(W_in, 512, ct * 64, jt * 64, wtin, 128);
    } else if (bid < 24) {
        int t3 = bid - 16;
        int kt = t3 >> 1, ct = t3 & 1;
        tr64_bf(W_out, 128, kt * 64, ct * 64, wtout, 256);
    } else {
        if (threadIdx.x < 64) part[threadIdx.x] = 0.0f;
    }
}

// ---------------------------------------------------------------------------
// K1 (MFMA bf16): xz = x @ W_in. 128(l) x 256(j) tile, 8 waves, K=128 in
// chunks of 64. grid (256, 2), block 512
// ---------------------------------------------------------------------------
__global__ __launch_bounds__(512) void k1_gemm_in(
    const float* __restrict__ x_hsi, const unsigned short* __restrict__ wtin,
    float* __restrict__ xh_raw, float* __restrict__ z_silu)
{
    __shared__ __align__(16) unsigned short Abf[128 * LSTR];   // rows = l
    __shared__ __align__(16) unsigned short Bbf[256 * LSTR];   // rows = j
    const int tid = threadIdx.x;
    const int R0  = blockIdx.x * 128;         // global row (b*L + l)
    const int b   = R0 >> 12;
    const int l0  = R0 & 4095;
    const int jbase = blockIdx.y * 256;

    const int w    = tid >> 6;                // 0..7
    const int lane = tid & 63;
    const int lm   = lane & 15;
    const int q    = lane >> 4;
    const int mbase = (w & 1) * 64;           // l-quadrant
    const int nbase = (w >> 1) * 64;          // j-quadrant (0..192)

    f32x4 acc[4][4];
    #pragma unroll
    for (int i = 0; i < 4; ++i)
        #pragma unroll
        for (int j = 0; j < 4; ++j) acc[i][j] = (f32x4){0.f, 0.f, 0.f, 0.f};

    const int cq = tid & 15;                  // c-quad within chunk (16*4=64)
    const int lq = tid >> 4;                  // l-quad (32*4=128)

    for (int kc = 0; kc < 128; kc += 64) {
        __syncthreads();
        // stage A: x[c][l] -> Abf[l][c_local] (transpose + packed cvt)
        {
            float v[4][4];
            #pragma unroll
            for (int t = 0; t < 4; ++t) {
                float4 f = *(const float4*)&x_hsi[((b * 128 + kc + cq * 4 + t) << 12) + l0 + lq * 4];
                v[t][0] = f.x; v[t][1] = f.y; v[t][2] = f.z; v[t][3] = f.w;
            }
            #pragma unroll
            for (int i = 0; i < 4; ++i) {
                unsigned p0 = pk2bf(v[0][i], v[1][i]);
                unsigned p1 = pk2bf(v[2][i], v[3][i]);
                unsigned long long u = (unsigned long long)p0 | ((unsigned long long)p1 << 32);
                *(unsigned long long*)&Abf[(lq * 4 + i) * LSTR + cq * 4] = u;
            }
        }
        // stage B: direct bf16 copy from wtin (256 rows x 8 segs)
        #pragma unroll
        for (int it = 0; it < 4; ++it) {
            int slot = tid + it * 512;
            int r = slot >> 3, seg = slot & 7;
            short8 vb = *(const short8*)&wtin[(size_t)(jbase + r) * 128 + kc + seg * 8];
            *(short8*)&Bbf[r * LSTR + seg * 8] = vb;
        }
        __syncthreads();
        #pragma unroll
        for (int kt = 0; kt < 2; ++kt) {
            short8 af[4], bfr[4];
            #pragma unroll
            for (int mt = 0; mt < 4; ++mt)
                af[mt] = *(const short8*)&Abf[(mbase + mt * 16 + lm) * LSTR + kt * 32 + q * 8];
            #pragma unroll
            for (int nt = 0; nt < 4; ++nt)
                bfr[nt] = *(const short8*)&Bbf[(nbase + nt * 16 + lm) * LSTR + kt * 32 + q * 8];
            #pragma unroll
            for (int mt = 0; mt < 4; ++mt)
                #pragma unroll
                for (int nt = 0; nt < 4; ++nt)
                    acc[mt][nt] = __builtin_amdgcn_mfma_f32_16x16x32_bf16(
                        af[mt], bfr[nt], acc[mt][nt], 0, 0, 0);
        }
    }

    const bool is_xh = (jbase == 0);
    #pragma unroll
    for (int mt = 0; mt < 4; ++mt) {
        #pragma unroll
        for (int r = 0; r < 4; ++r) {
            int row = R0 + mbase + mt * 16 + q * 4 + r;
            #pragma unroll
            for (int nt = 0; nt < 4; ++nt) {
                int col = nbase + nt * 16 + lm;     // 0..255
                float val = acc[mt][nt][r];
                if (is_xh) xh_raw[row * 256 + col] = val;
                else       z_silu[row * 256 + col] = silu_fast(val);
            }
        }
    }
}

// ---------------------------------------------------------------------------
// K4: xdbl = conv_silu(xh) @ W_x tiled GEMM (fp32) + emit xcbf (bf16 conv out).
// grid 256, block 256
// ---------------------------------------------------------------------------
__global__ __launch_bounds__(256) void k4_xdbl(
    const float* __restrict__ xh_raw, const float* __restrict__ conv_w,
    const float* __restrict__ conv_b, const float* __restrict__ W_x,
    float* __restrict__ xdbl, unsigned short* __restrict__ xcbf)
{
    __shared__ float xcs[128][68];
    __shared__ float wxs[64 * 40];
    __shared__ float cw0[256], cw1[256], cbs[256];
    const int tid = threadIdx.x;
    cw0[tid] = conv_w[2 * tid];
    cw1[tid] = conv_w[2 * tid + 1];
    cbs[tid] = conv_b[tid];

    const int R0 = blockIdx.x * 128;
    const int tc = tid & 7;
    const int tr = tid >> 3;

    float acc[4][5];
    #pragma unroll
    for (int i = 0; i < 4; ++i)
        #pragma unroll
        for (int j = 0; j < 5; ++j) acc[i][j] = 0.0f;

    for (int kc = 0; kc < 256; kc += 64) {
        __syncthreads();
        #pragma unroll
        for (int it = 0; it < 3; ++it) {
            int i4 = tid + it * 256;
            if (i4 < 640) ((float4*)wxs)[i4] = ((const float4*)&W_x[kc * 40])[i4];
        }
        #pragma unroll
        for (int it = 0; it < 8; ++it) {
            int idx = tid + it * 256;
            int r = idx >> 4, qq = idx & 15;
            int row = R0 + r;
            float4 cur = *(const float4*)&xh_raw[row * 256 + kc + qq * 4];
            float4 prv = make_float4(0.f, 0.f, 0.f, 0.f);
            if ((row & 4095) != 0)
                prv = *(const float4*)&xh_raw[(row - 1) * 256 + kc + qq * 4];
            int d = kc + qq * 4;
            float4 o;
            o.x = silu_fast(prv.x * cw0[d+0] + cur.x * cw1[d+0] + cbs[d+0]);
            o.y = silu_fast(prv.y * cw0[d+1] + cur.y * cw1[d+1] + cbs[d+1]);
            o.z = silu_fast(prv.z * cw0[d+2] + cur.z * cw1[d+2] + cbs[d+2]);
            o.w = silu_fast(prv.w * cw0[d+3] + cur.w * cw1[d+3] + cbs[d+3]);
            *(float4*)&xcs[r][qq * 4] = o;
            unsigned p0 = pk2bf(o.x, o.y), p1 = pk2bf(o.z, o.w);
            unsigned long long u = (unsigned long long)p0 | ((unsigned long long)p1 << 32);
            *(unsigned long long*)&xcbf[(size_t)row * 256 + d] = u;
        }
        __syncthreads();
        #pragma unroll 2
        for (int k = 0; k < 64; ++k) {
            float wv[5];
            #pragma unroll
            for (int j = 0; j < 5; ++j) wv[j] = wxs[k * 40 + tc * 5 + j];
            #pragma unroll
            for (int i = 0; i < 4; ++i) {
                float a = xcs[tr * 4 + i][k];
                #pragma unroll
                for (int j = 0; j < 5; ++j) acc[i][j] = fmaf(a, wv[j], acc[i][j]);
            }
        }
    }
    #pragma unroll
    for (int i = 0; i < 4; ++i) {
        int row = R0 + tr * 4 + i;
        #pragma unroll
        for (int j = 0; j < 5; ++j) xdbl[row * 40 + tc * 5 + j] = acc[i][j];
    }
}

// ---------------------------------------------------------------------------
// Scan pass 1: local h (h_in=0); emits dtv per step + dtsum per chunk.
// xdbl staged in LDS; xc from xcbf. grid (NCH, BATCH), block 256
// ---------------------------------------------------------------------------
__global__ __launch_bounds__(256) void k6_scan1(
    const unsigned short* __restrict__ xcbf, const float* __restrict__ xdbl,
    const float* __restrict__ W_dt, const float* __restrict__ b_dt,
    const float* __restrict__ A_log,
    float* __restrict__ hend, float* __restrict__ dtsg,
    float* __restrict__ dtvg)
{
    __shared__ float xd[TCH * 40];
    const int d = threadIdx.x;
    const int chunk = blockIdx.x;
    const int b = blockIdx.y;
    const int t0 = b * LSEQ + chunk * TCH;

    {
        const float4* src = (const float4*)&xdbl[t0 * 40];
        if (d < 160) ((float4*)xd)[d] = src[d];
    }

    float A[16];
    #pragma unroll
    for (int qq = 0; qq < 4; ++qq) {
        float4 al = *(const float4*)&A_log[d * 16 + qq * 4];
        A[qq*4+0] = -__expf(al.x); A[qq*4+1] = -__expf(al.y);
        A[qq*4+2] = -__expf(al.z); A[qq*4+3] = -__expf(al.w);
    }
    bool fast = true;
    #pragma unroll
    for (int n = 1; n < 16; ++n)
        fast = fast && (fabsf(A[n] - (n + 1) * A[0]) <= 1e-4f * fabsf(A[n]) + 1e-7f);

    float wdt[8];
    #pragma unroll
    for (int r = 0; r < 8; ++r) wdt[r] = W_dt[r * 256 + d];
    const float bdt = b_dt[d];

    f32x2 h2[8];
    #pragma unroll
    for (int j = 0; j < 8; ++j) h2[j] = (f32x2){0.f, 0.f};
    float dtsum = 0.f;
    __syncthreads();

    #pragma unroll 2
    for (int tt = 0; tt < TCH; ++tt) {
        const int row = t0 + tt;
        float xcv = bf2f(xcbf[(size_t)row * 256 + d]);

        const float* xr = &xd[tt * 40];
        float dl[8];
        *(float4*)&dl[0] = *(const float4*)&xr[0];
        *(float4*)&dl[4] = *(const float4*)&xr[4];
        float dtr = bdt;
        #pragma unroll
        for (int r = 0; r < 8; ++r) dtr = fmaf(dl[r], wdt[r], dtr);
        float dtv = softplus_fast(dtr);
        dtsum += dtv;
        float dtx = dtv * xcv;
        dtvg[(size_t)row * 256 + d] = dtv;

        float Bt[16] __attribute__((aligned(16)));
        #pragma unroll
        for (int qq = 0; qq < 4; ++qq)
            *(float4*)&Bt[qq * 4] = *(const float4*)&xr[8 + qq * 4];

        float dA[16] __attribute__((aligned(16)));
        dA_powers(dtv, A, fast, dA);
        const f32x2* dA2 = (const f32x2*)dA;
        const f32x2* Bt2 = (const f32x2*)Bt;
        f32x2 dtx2 = (f32x2){dtx, dtx};
        #pragma unroll
        for (int j = 0; j < 8; ++j)
            h2[j] = dA2[j] * h2[j] + dtx2 * Bt2[j];
    }

    const float* hf = (const float*)h2;
    const int base = ((b * NCH + chunk) * 256 + d) * 16;
    #pragma unroll
    for (int qq = 0; qq < 4; ++qq)
        *(float4*)&hend[base + qq * 4] = make_float4(hf[qq*4], hf[qq*4+1], hf[qq*4+2], hf[qq*4+3]);
    dtsg[(b * NCH + chunk) * 256 + d] = dtsum;
}

// ---------------------------------------------------------------------------
// Scan pass 2: sequential combine with P(c) = exp(dtsum(c)*A[n]) computed
// on the fly; hx: hend -> hin in-place. 8-deep prefetch. grid 128, block 256
// ---------------------------------------------------------------------------
__global__ __launch_bounds__(256) void k7_combine(
    const float* __restrict__ dtsg, const float* __restrict__ A_log,
    float* __restrict__ hx)
{
    const int idx = blockIdx.x * 256 + threadIdx.x;   // b*4096 + d*16 + n
    const int b = idx >> 12;
    const int rem = idx & 4095;
    const int d = rem >> 4, n = rem & 15;
    const float An = -__expf(A_log[d * 16 + n]);
    const int base = b * NCH * 4096 + rem;            // hx index, +4096/chunk
    const int sbase = b * NCH * 256 + d;              // dtsg index, +256/chunk
    float h = 0.f;
    float Sb[8], Eb[8];
    #pragma unroll
    for (int j = 0; j < 8; ++j) {
        Sb[j] = dtsg[sbase + j * 256];
        Eb[j] = hx[base + j * 4096];
    }
    for (int g = 0; g < NCH / 8; ++g) {
        const int o  = base + g * 32768;
        const int so = sbase + g * 2048;
        float Sn[8] = {0,0,0,0,0,0,0,0}, En[8] = {0,0,0,0,0,0,0,0};
        if (g < NCH / 8 - 1) {
            #pragma unroll
            for (int j = 0; j < 8; ++j) {
                Sn[j] = dtsg[so + 2048 + j * 256];
                En[j] = hx[o + 32768 + j * 4096];
            }
        }
        #pragma unroll
        for (int j = 0; j < 8; ++j) {
            hx[o + j * 4096] = h;
            float P = __expf(Sb[j] * An);
            h = fmaf(P, h, Eb[j]);
        }
        #pragma unroll
        for (int j = 0; j < 8; ++j) { Sb[j] = Sn[j]; Eb[j] = En[j]; }
    }
}

// ---------------------------------------------------------------------------
// Scan pass 3: replay with h_in using stored dtv (dtx = dtv*xc recomputed);
// y -> ybf (bf16). grid (NCH, BATCH), block 256
// ---------------------------------------------------------------------------
__global__ __launch_bounds__(256) void k8_scan2(
    const unsigned short* __restrict__ xcbf, const float* __restrict__ xdbl,
    const float* __restrict__ dtvg, const float* __restrict__ A_log,
    const float* __restrict__ Dvec, const float* __restrict__ hin,
    const float* __restrict__ zsilu, unsigned short* __restrict__ ybf)
{
    __shared__ float xd[TCH * 40];
    const int d = threadIdx.x;
    const int chunk = blockIdx.x;
    const int b = blockIdx.y;
    const int t0 = b * LSEQ + chunk * TCH;

    {
        const float4* src = (const float4*)&xdbl[t0 * 40];
        if (d < 160) ((float4*)xd)[d] = src[d];
    }

    float A[16];
    #pragma unroll
    for (int qq = 0; qq < 4; ++qq) {
        float4 al = *(const float4*)&A_log[d * 16 + qq * 4];
        A[qq*4+0] = -__expf(al.x); A[qq*4+1] = -__expf(al.y);
        A[qq*4+2] = -__expf(al.z); A[qq*4+3] = -__expf(al.w);
    }
    bool fast = true;
    #pragma unroll
    for (int n = 1; n < 16; ++n)
        fast = fast && (fabsf(A[n] - (n + 1) * A[0]) <= 1e-4f * fabsf(A[n]) + 1e-7f);

    const float Dd = Dvec[d];

    f32x2 h2[8];
    const int hbase = ((b * NCH + chunk) * 256 + d) * 16;
    {
        float hf[16];
        #pragma unroll
        for (int qq = 0; qq < 4; ++qq) {
            float4 hv = *(const float4*)&hin[hbase + qq * 4];
            hf[qq*4+0] = hv.x; hf[qq*4+1] = hv.y; hf[qq*4+2] = hv.z; hf[qq*4+3] = hv.w;
        }
        #pragma unroll
        for (int j = 0; j < 8; ++j) h2[j] = (f32x2){hf[2*j], hf[2*j+1]};
    }
    __syncthreads();

    #pragma unroll 2
    for (int tt = 0; tt < TCH; ++tt) {
        const int row = t0 + tt;
        const size_t gi = (size_t)row * 256 + d;
        float dtv = dtvg[gi];
        float xcv = bf2f(xcbf[gi]);
        float dtx = dtv * xcv;

        const float* xr = &xd[tt * 40];
        float Bt[16] __attribute__((aligned(16)));
        float Ct[16] __attribute__((aligned(16)));
        #pragma unroll
        for (int qq = 0; qq < 4; ++qq) {
            *(float4*)&Bt[qq * 4] = *(const float4*)&xr[8 + qq * 4];
            *(float4*)&Ct[qq * 4] = *(const float4*)&xr[24 + qq * 4];
        }

        float dA[16] __attribute__((aligned(16)));
        dA_powers(dtv, A, fast, dA);
        const f32x2* dA2 = (const f32x2*)dA;
        const f32x2* Bt2 = (const f32x2*)Bt;
        const f32x2* Ct2 = (const f32x2*)Ct;
        f32x2 dtx2 = (f32x2){dtx, dtx};
        f32x2 yv2 = (f32x2){0.f, 0.f};
        #pragma unroll
        for (int j = 0; j < 8; ++j) {
            h2[j] = dA2[j] * h2[j] + dtx2 * Bt2[j];
            yv2 = yv2 + h2[j] * Ct2[j];
        }
        float yv = yv2.x + yv2.y;
        yv = fmaf(Dd, xcv, yv);
        ybf[gi] = f2bf(yv * zsilu[gi]);
    }
}

// ---------------------------------------------------------------------------
// K9 (MFMA bf16): out_bf[b,c,l] = bf16( sum_k y[b,l,k] * W_out[k,c] ).
// Fused GN partial sums in fp32 (atomics into part). grid 256, block 256
// ---------------------------------------------------------------------------
__global__ __launch_bounds__(256) void k9_gemm_out(
    const unsigned short* __restrict__ ybf, const unsigned short* __restrict__ wtout,
    unsigned short* __restrict__ out_bf, float* __restrict__ part)
{
    __shared__ __align__(16) unsigned short Abf[128 * LSTR];   // rows = c
    __shared__ __align__(16) unsigned short Bbf[128 * LSTR];   // rows = l
    const int tid = threadIdx.x;
    const int R0 = blockIdx.x * 128;
    const int b  = R0 >> 12;
    const int l0 = R0 & 4095;

    const int w    = tid >> 6;
    const int lane = tid & 63;
    const int lm   = lane & 15;
    const int q    = lane >> 4;
    const int mbase = (w & 1) * 64;           // c-quadrant
    const int nbase = (w >> 1) * 64;          // l-quadrant

    f32x4 acc[4][4];
    #pragma unroll
    for (int i = 0; i < 4; ++i)
        #pragma unroll
        for (int j = 0; j < 4; ++j) acc[i][j] = (f32x4){0.f, 0.f, 0.f, 0.f};

    for (int kc = 0; kc < 256; kc += 64) {
        __syncthreads();
        #pragma unroll
        for (int it = 0; it < 4; ++it) {
            int slot = tid + it * 256;        // 128 rows x 8 segs
            int r = slot >> 3, seg = slot & 7;
            short8 va = *(const short8*)&wtout[(size_t)r * 256 + kc + seg * 8];
            *(short8*)&Abf[r * LSTR + seg * 8] = va;
            short8 vb = *(const short8*)&ybf[(size_t)(R0 + r) * 256 + kc + seg * 8];
            *(short8*)&Bbf[r * LSTR + seg * 8] = vb;
        }
        __syncthreads();
        #pragma unroll
        for (int kt = 0; kt < 2; ++kt) {
            short8 af[4], bfr[4];
            #pragma unroll
            for (int mt = 0; mt < 4; ++mt)
                af[mt] = *(const short8*)&Abf[(mbase + mt * 16 + lm) * LSTR + kt * 32 + q * 8];
            #pragma unroll
            for (int nt = 0; nt < 4; ++nt)
                bfr[nt] = *(const short8*)&Bbf[(nbase + nt * 16 + lm) * LSTR + kt * 32 + q * 8];
            #pragma unroll
            for (int mt = 0; mt < 4; ++mt)
                #pragma unroll
                for (int nt = 0; nt < 4; ++nt)
                    acc[mt][nt] = __builtin_amdgcn_mfma_f32_16x16x32_bf16(
                        af[mt], bfr[nt], acc[mt][nt], 0, 0, 0);
        }
    }

    #pragma unroll
    for (int mt = 0; mt < 4; ++mt) {
        #pragma unroll
        for (int r = 0; r < 4; ++r) {
            int c = mbase + mt * 16 + q * 4 + r;
            long base = (long)(b * 128 + c) * 4096 + l0;
            #pragma unroll
            for (int nt = 0; nt < 4; ++nt)
                out_bf[base + nbase + nt * 16 + lm] = f2bf(acc[mt][nt][r]);
        }
    }

    // fused GroupNorm partial sums (fp32 from accumulators)
    float s0 = 0.f, q0 = 0.f, s1 = 0.f, q1 = 0.f;
    #pragma unroll
    for (int mt = 0; mt < 4; ++mt)
        #pragma unroll
        for (int nt = 0; nt < 4; ++nt)
            #pragma unroll
            for (int r = 0; r < 4; ++r) {
                float v = acc[mt][nt][r];
                if (mt < 2) { s0 += v; q0 += v * v; }
                else        { s1 += v; q1 += v * v; }
            }
    #pragma unroll
    for (int off = 32; off > 0; off >>= 1) {
        s0 += __shfl_down(s0, off, 64);
        q0 += __shfl_down(q0, off, 64);
        s1 += __shfl_down(s1, off, 64);
        q1 += __shfl_down(q1, off, 64);
    }
    if (lane == 0) {
        int g0 = mbase >> 5;
        atomicAdd(&part[(b * 4 + g0) * 2],     s0);
        atomicAdd(&part[(b * 4 + g0) * 2 + 1], q0);
        atomicAdd(&part[(b * 4 + g0 + 1) * 2],     s1);
        atomicAdd(&part[(b * 4 + g0 + 1) * 2 + 1], q1);
    }
}

// K10c: apply GN + silu + residual (stat computed inline from part; out_mm
// read as bf16). grid 4096, block 256
__global__ __launch_bounds__(256) void k10c_apply(
    const unsigned short* __restrict__ out_bf, const float* __restrict__ part,
    const float* __restrict__ gamma, const float* __restrict__ beta,
    const float* __restrict__ x_hsi, float* __restrict__ out)
{
    __shared__ float sstat[64];
    if (threadIdx.x < 32) {
        float S = part[threadIdx.x * 2];
        float Q = part[threadIdx.x * 2 + 1];
        const float inv_n = 1.0f / 131072.0f;
        float mean = S * inv_n;
        float var  = Q * inv_n - mean * mean;
        sstat[threadIdx.x * 2]     = mean;
        sstat[threadIdx.x * 2 + 1] = rsqrtf(var + 1e-5f);
    }
    __syncthreads();
    const int idx4 = blockIdx.x * 256 + threadIdx.x;
    const int flat = idx4 * 4;
    const int c = (flat >> 12) & 127;
    const int b = flat >> 19;
    const int g = c >> 5;
    const float mean = sstat[(b * 4 + g) * 2];
    const float inv  = sstat[(b * 4 + g) * 2 + 1];
    const float ga = gamma[c], be = beta[c];
    ushort4 u = *(const ushort4*)&out_bf[flat];
    float4 r = *(const float4*)&x_hsi[flat];
    float vv[4] = {bf2f(u.x), bf2f(u.y), bf2f(u.z), bf2f(u.w)};
    float rr[4] = {r.x, r.y, r.z, r.w};
    float o[4];
    #pragma unroll
    for (int qq = 0; qq < 4; ++qq) {
        float xn = (vv[qq] - mean) * inv;
        float gv = xn * ga + be;
        o[qq] = silu_fast(gv) + rr[qq];
    }
    *(float4*)&out[flat] = make_float4(o[0], o[1], o[2], o[3]);
}

// ---------------------------------------------------------------------------
extern "C" void kernel_launch(void* const* d_in, const int* in_sizes, int n_in,
                              void* d_out, int out_size, void* d_ws, size_t ws_size,
                              hipStream_t stream)
{
    const float* x_hsi  = (const float*)d_in[0];
    const float* W_in   = (const float*)d_in[1];
    const float* conv_w = (const float*)d_in[2];
    const float* conv_b = (const float*)d_in[3];
    const float* W_x    = (const float*)d_in[4];
    const float* W_dt   = (const float*)d_in[5];
    const float* b_dt   = (const float*)d_in[6];
    const float* A_log  = (const float*)d_in[7];
    const float* Dv     = (const float*)d_in[8];
    const float* W_out  = (const float*)d_in[9];
    const float* gnw    = (const float*)d_in[10];
    const float* gnb    = (const float*)d_in[11];

    float* ws = (float*)d_ws;
    float* xh_raw = ws + 0;            // 8,388,608 f (ybf aliases after k4)
    float* zsilu  = ws + 8388608;      // 8,388,608 f
    float* xdbl   = ws + 16777216;     // 327,680 f
    float* hx     = ws + 17104896;     // 8,388,608 f (NCH=256)  hend->hin in-place
    float* dtvg   = ws + 25493504;     // 8,388,608 f
    float* dtsg   = ws + 33882112;     // 524,288 f
    unsigned short* xcbf = (unsigned short*)(ws + 34406400);  // 8,388,608 us
    unsigned short* out_bf = (unsigned short*)(ws + 38600704); // 4,194,304 us
    float* part   = ws + 40697856;     // 64 f
    unsigned short* wtin  = (unsigned short*)(ws + 40697984); // 65,536 us
    unsigned short* wtout = (unsigned short*)(ws + 40730752); // 32,768 us
    unsigned short* ybf   = (unsigned short*)xh_raw;          // alias: xh dead after k4
    float* outp   = (float*)d_out;

    k0_setup<<<25, 256, 0, stream>>>(W_in, W_out, wtin, wtout, part);
    k1_gemm_in<<<dim3(256, 2), 512, 0, stream>>>(x_hsi, wtin, xh_raw, zsilu);
    k4_xdbl<<<256, 256, 0, stream>>>(xh_raw, conv_w, conv_b, W_x, xdbl, xcbf);
    k6_scan1<<<dim3(NCH, BATCH), 256, 0, stream>>>(xcbf, xdbl, W_dt, b_dt, A_log,
                                                   hx, dtsg, dtvg);
    k7_combine<<<128, 256, 0, stream>>>(dtsg, A_log, hx);
    k8_scan2<<<dim3(NCH, BATCH), 256, 0, stream>>>(xcbf, xdbl, dtvg,
                                                   A_log, Dv, hx, zsilu, ybf);
    k9_gemm_out<<<256, 256, 0, stream>>>(ybf, wtout, out_bf, part);
    k10c_apply<<<4096, 256, 0, stream>>>(out_bf, part, gnw, gnb, x_hsi, outp);
}

// Round 11
// 236.534 us; speedup vs baseline: 1.0446x; 1.0446x over previous
//
#include <hip/hip_runtime.h>
#include <hip/hip_bf16.h>
#include <math.h>

// Problem constants
#define BATCH   8
#define LSEQ    4096      // 64*64
#define CMODEL  128
#define DIN     256
#define NSTATE  16
#define RRANK   8
#define NCH     128       // chunks per sequence
#define TCH     32        // timesteps per chunk (NCH*TCH == LSEQ)

typedef __attribute__((ext_vector_type(8))) short short8;
typedef __attribute__((ext_vector_type(4))) float f32x4;
typedef __attribute__((ext_vector_type(2))) float f32x2;

__device__ __forceinline__ float sigmoid_fast(float x) {
    return __builtin_amdgcn_rcpf(1.0f + __expf(-x));
}
__device__ __forceinline__ float silu_fast(float x) { return x * sigmoid_fast(x); }
__device__ __forceinline__ float softplus_fast(float x) {
    return fmaxf(x, 0.0f) + __logf(1.0f + __expf(-fabsf(x)));
}
__device__ __forceinline__ unsigned short f2bf(float f) {
    unsigned u = __float_as_uint(f);
    return (unsigned short)((u + 0x7FFFu + ((u >> 16) & 1u)) >> 16);   // RNE
}
__device__ __forceinline__ float bf2f(unsigned short u) {
    return __uint_as_float(((unsigned)u) << 16);
}
// packed fp32x2 -> bf16x2 (v_cvt_pk_bf16_f32 on gfx950); a -> low, b -> high
__device__ __forceinline__ unsigned pk2bf(float a, float b) {
    __hip_bfloat162 t = __float22bfloat162_rn(make_float2(a, b));
    unsigned r;
    __builtin_memcpy(&r, &t, 4);
    return r;
}

// dA[n] = exp(dtv*A[n]); A[n] == (n+1)*A[0] fast path: 1 exp + mul chain.
__device__ __forceinline__ void dA_powers(float dtv, const float* A, bool fast,
                                          float* dA)
{
    if (fast) {
        float e1 = __expf(dtv * A[0]);
        float e2 = e1 * e1;
        float e4 = e2 * e2;
        float e8 = e4 * e4;
        dA[0] = e1;        dA[1] = e2;        dA[2] = e2 * e1;   dA[3] = e4;
        dA[4] = e4 * e1;   dA[5] = e4 * e2;   dA[6] = e4 * dA[2]; dA[7] = e8;
        dA[8] = e8 * e1;   dA[9] = e8 * e2;   dA[10] = e8 * dA[2]; dA[11] = e8 * e4;
        dA[12] = e8 * dA[4]; dA[13] = e8 * dA[5]; dA[14] = e8 * dA[6]; dA[15] = e8 * e8;
    } else {
        #pragma unroll
        for (int n = 0; n < 16; ++n) dA[n] = __expf(dtv * A[n]);
    }
}

#define LSTR 72   // LDS row stride (bf16 units): 64 data + 8 pad; 2-way max = free

// ---------------------------------------------------------------------------
// K0: weight transposes (tiny) + part zero. grid 25, block 256
// ---------------------------------------------------------------------------
__device__ __forceinline__ void tr64_bf(const float* __restrict__ src, int lds,
                                        int r0, int c0,
                                        unsigned short* __restrict__ dst, int ldd)
{
    __shared__ float ts[64][65];
    const int tid = threadIdx.x;
    #pragma unroll
    for (int it = 0; it < 4; ++it) {
        int slot = tid + it * 256;
        int i = slot >> 4, j4 = slot & 15;
        float4 v = *(const float4*)&src[(size_t)(r0 + i) * lds + c0 + j4 * 4];
        ts[i][j4*4+0] = v.x; ts[i][j4*4+1] = v.y;
        ts[i][j4*4+2] = v.z; ts[i][j4*4+3] = v.w;
    }
    __syncthreads();
    #pragma unroll
    for (int it = 0; it < 4; ++it) {
        int slot = tid + it * 256;
        int row = slot >> 4, c4 = slot & 15;
        unsigned p0 = pk2bf(ts[c4*4+0][row], ts[c4*4+1][row]);
        unsigned p1 = pk2bf(ts[c4*4+2][row], ts[c4*4+3][row]);
        unsigned long long u = (unsigned long long)p0 | ((unsigned long long)p1 << 32);
        *(unsigned long long*)&dst[(size_t)(c0 + row) * ldd + r0 + c4 * 4] = u;
    }
}

__global__ __launch_bounds__(256) void k0_setup(
    const float* __restrict__ W_in, const float* __restrict__ W_out,
    unsigned short* __restrict__ wtin, unsigned short* __restrict__ wtout,
    float* __restrict__ part)
{
    const int bid = blockIdx.x;
    if (bid < 16) {
        int ct = bid >> 3, jt = bid & 7;
        tr64_bf(W_in, 512, ct * 64, jt * 64, wtin, 128);
    } else if (bid < 24) {
        int t3 = bid - 16;
        int kt = t3 >> 1, ct = t3 & 1;
        tr64_bf(W_out, 128, kt * 64, ct * 64, wtout, 256);
    } else {
        if (threadIdx.x < 64) part[threadIdx.x] = 0.0f;
    }
}

// ---------------------------------------------------------------------------
// K1 (MFMA bf16): xz = x @ W_in. 128(l) x 256(j) tile, 8 waves, K=128 in
// chunks of 64. grid (256, 2), block 512
// ---------------------------------------------------------------------------
__global__ __launch_bounds__(512) void k1_gemm_in(
    const float* __restrict__ x_hsi, const unsigned short* __restrict__ wtin,
    float* __restrict__ xh_raw, float* __restrict__ z_silu)
{
    __shared__ __align__(16) unsigned short Abf[128 * LSTR];   // rows = l
    __shared__ __align__(16) unsigned short Bbf[256 * LSTR];   // rows = j
    const int tid = threadIdx.x;
    const int R0  = blockIdx.x * 128;         // global row (b*L + l)
    const int b   = R0 >> 12;
    const int l0  = R0 & 4095;
    const int jbase = blockIdx.y * 256;

    const int w    = tid >> 6;                // 0..7
    const int lane = tid & 63;
    const int lm   = lane & 15;
    const int q    = lane >> 4;
    const int mbase = (w & 1) * 64;           // l-quadrant
    const int nbase = (w >> 1) * 64;          // j-quadrant (0..192)

    f32x4 acc[4][4];
    #pragma unroll
    for (int i = 0; i < 4; ++i)
        #pragma unroll
        for (int j = 0; j < 4; ++j) acc[i][j] = (f32x4){0.f, 0.f, 0.f, 0.f};

    const int cq = tid & 15;                  // c-quad within chunk (16*4=64)
    const int lq = tid >> 4;                  // l-quad (32*4=128)

    for (int kc = 0; kc < 128; kc += 64) {
        __syncthreads();
        // stage A: x[c][l] -> Abf[l][c_local] (transpose + packed cvt)
        {
            float v[4][4];
            #pragma unroll
            for (int t = 0; t < 4; ++t) {
                float4 f = *(const float4*)&x_hsi[((b * 128 + kc + cq * 4 + t) << 12) + l0 + lq * 4];
                v[t][0] = f.x; v[t][1] = f.y; v[t][2] = f.z; v[t][3] = f.w;
            }
            #pragma unroll
            for (int i = 0; i < 4; ++i) {
                unsigned p0 = pk2bf(v[0][i], v[1][i]);
                unsigned p1 = pk2bf(v[2][i], v[3][i]);
                unsigned long long u = (unsigned long long)p0 | ((unsigned long long)p1 << 32);
                *(unsigned long long*)&Abf[(lq * 4 + i) * LSTR + cq * 4] = u;
            }
        }
        // stage B: direct bf16 copy from wtin (256 rows x 8 segs)
        #pragma unroll
        for (int it = 0; it < 4; ++it) {
            int slot = tid + it * 512;
            int r = slot >> 3, seg = slot & 7;
            short8 vb = *(const short8*)&wtin[(size_t)(jbase + r) * 128 + kc + seg * 8];
            *(short8*)&Bbf[r * LSTR + seg * 8] = vb;
        }
        __syncthreads();
        #pragma unroll
        for (int kt = 0; kt < 2; ++kt) {
            short8 af[4], bfr[4];
            #pragma unroll
            for (int mt = 0; mt < 4; ++mt)
                af[mt] = *(const short8*)&Abf[(mbase + mt * 16 + lm) * LSTR + kt * 32 + q * 8];
            #pragma unroll
            for (int nt = 0; nt < 4; ++nt)
                bfr[nt] = *(const short8*)&Bbf[(nbase + nt * 16 + lm) * LSTR + kt * 32 + q * 8];
            #pragma unroll
            for (int mt = 0; mt < 4; ++mt)
                #pragma unroll
                for (int nt = 0; nt < 4; ++nt)
                    acc[mt][nt] = __builtin_amdgcn_mfma_f32_16x16x32_bf16(
                        af[mt], bfr[nt], acc[mt][nt], 0, 0, 0);
        }
    }

    const bool is_xh = (jbase == 0);
    #pragma unroll
    for (int mt = 0; mt < 4; ++mt) {
        #pragma unroll
        for (int r = 0; r < 4; ++r) {
            int row = R0 + mbase + mt * 16 + q * 4 + r;
            #pragma unroll
            for (int nt = 0; nt < 4; ++nt) {
                int col = nbase + nt * 16 + lm;     // 0..255
                float val = acc[mt][nt][r];
                if (is_xh) xh_raw[row * 256 + col] = val;
                else       z_silu[row * 256 + col] = silu_fast(val);
            }
        }
    }
}

// ---------------------------------------------------------------------------
// K4: xdbl = conv_silu(xh) @ W_x tiled GEMM (fp32) + emit xcbf (bf16 conv out).
// grid 256, block 256
// ---------------------------------------------------------------------------
__global__ __launch_bounds__(256) void k4_xdbl(
    const float* __restrict__ xh_raw, const float* __restrict__ conv_w,
    const float* __restrict__ conv_b, const float* __restrict__ W_x,
    float* __restrict__ xdbl, unsigned short* __restrict__ xcbf)
{
    __shared__ float xcs[128][68];
    __shared__ float wxs[64 * 40];
    __shared__ float cw0[256], cw1[256], cbs[256];
    const int tid = threadIdx.x;
    cw0[tid] = conv_w[2 * tid];
    cw1[tid] = conv_w[2 * tid + 1];
    cbs[tid] = conv_b[tid];

    const int R0 = blockIdx.x * 128;
    const int tc = tid & 7;
    const int tr = tid >> 3;

    float acc[4][5];
    #pragma unroll
    for (int i = 0; i < 4; ++i)
        #pragma unroll
        for (int j = 0; j < 5; ++j) acc[i][j] = 0.0f;

    for (int kc = 0; kc < 256; kc += 64) {
        __syncthreads();
        #pragma unroll
        for (int it = 0; it < 3; ++it) {
            int i4 = tid + it * 256;
            if (i4 < 640) ((float4*)wxs)[i4] = ((const float4*)&W_x[kc * 40])[i4];
        }
        #pragma unroll
        for (int it = 0; it < 8; ++it) {
            int idx = tid + it * 256;
            int r = idx >> 4, qq = idx & 15;
            int row = R0 + r;
            float4 cur = *(const float4*)&xh_raw[row * 256 + kc + qq * 4];
            float4 prv = make_float4(0.f, 0.f, 0.f, 0.f);
            if ((row & 4095) != 0)
                prv = *(const float4*)&xh_raw[(row - 1) * 256 + kc + qq * 4];
            int d = kc + qq * 4;
            float4 o;
            o.x = silu_fast(prv.x * cw0[d+0] + cur.x * cw1[d+0] + cbs[d+0]);
            o.y = silu_fast(prv.y * cw0[d+1] + cur.y * cw1[d+1] + cbs[d+1]);
            o.z = silu_fast(prv.z * cw0[d+2] + cur.z * cw1[d+2] + cbs[d+2]);
            o.w = silu_fast(prv.w * cw0[d+3] + cur.w * cw1[d+3] + cbs[d+3]);
            *(float4*)&xcs[r][qq * 4] = o;
            unsigned p0 = pk2bf(o.x, o.y), p1 = pk2bf(o.z, o.w);
            unsigned long long u = (unsigned long long)p0 | ((unsigned long long)p1 << 32);
            *(unsigned long long*)&xcbf[(size_t)row * 256 + d] = u;
        }
        __syncthreads();
        #pragma unroll 2
        for (int k = 0; k < 64; ++k) {
            float wv[5];
            #pragma unroll
            for (int j = 0; j < 5; ++j) wv[j] = wxs[k * 40 + tc * 5 + j];
            #pragma unroll
            for (int i = 0; i < 4; ++i) {
                float a = xcs[tr * 4 + i][k];
                #pragma unroll
                for (int j = 0; j < 5; ++j) acc[i][j] = fmaf(a, wv[j], acc[i][j]);
            }
        }
    }
    #pragma unroll
    for (int i = 0; i < 4; ++i) {
        int row = R0 + tr * 4 + i;
        #pragma unroll
        for (int j = 0; j < 5; ++j) xdbl[row * 40 + tc * 5 + j] = acc[i][j];
    }
}

// ---------------------------------------------------------------------------
// Scan pass 1: local h (h_in=0); emits dtv per step + dtsum per chunk.
// xdbl staged in LDS; xc from xcbf. grid (NCH, BATCH), block 256
// ---------------------------------------------------------------------------
__global__ __launch_bounds__(256) void k6_scan1(
    const unsigned short* __restrict__ xcbf, const float* __restrict__ xdbl,
    const float* __restrict__ W_dt, const float* __restrict__ b_dt,
    const float* __restrict__ A_log,
    float* __restrict__ hend, float* __restrict__ dtsg,
    float* __restrict__ dtvg)
{
    __shared__ float xd[TCH * 40];
    const int d = threadIdx.x;
    const int chunk = blockIdx.x;
    const int b = blockIdx.y;
    const int t0 = b * LSEQ + chunk * TCH;

    {
        const float4* src = (const float4*)&xdbl[t0 * 40];
        if (d < 256) ((float4*)xd)[d] = src[d];
        int i2 = d + 256;
        if (i2 < 320) ((float4*)xd)[i2] = src[i2];
    }

    float A[16];
    #pragma unroll
    for (int qq = 0; qq < 4; ++qq) {
        float4 al = *(const float4*)&A_log[d * 16 + qq * 4];
        A[qq*4+0] = -__expf(al.x); A[qq*4+1] = -__expf(al.y);
        A[qq*4+2] = -__expf(al.z); A[qq*4+3] = -__expf(al.w);
    }
    bool fast = true;
    #pragma unroll
    for (int n = 1; n < 16; ++n)
        fast = fast && (fabsf(A[n] - (n + 1) * A[0]) <= 1e-4f * fabsf(A[n]) + 1e-7f);

    float wdt[8];
    #pragma unroll
    for (int r = 0; r < 8; ++r) wdt[r] = W_dt[r * 256 + d];
    const float bdt = b_dt[d];

    f32x2 h2[8];
    #pragma unroll
    for (int j = 0; j < 8; ++j) h2[j] = (f32x2){0.f, 0.f};
    float dtsum = 0.f;
    __syncthreads();

    #pragma unroll 2
    for (int tt = 0; tt < TCH; ++tt) {
        const int row = t0 + tt;
        float xcv = bf2f(xcbf[(size_t)row * 256 + d]);

        const float* xr = &xd[tt * 40];
        float dl[8];
        *(float4*)&dl[0] = *(const float4*)&xr[0];
        *(float4*)&dl[4] = *(const float4*)&xr[4];
        float dtr = bdt;
        #pragma unroll
        for (int r = 0; r < 8; ++r) dtr = fmaf(dl[r], wdt[r], dtr);
        float dtv = softplus_fast(dtr);
        dtsum += dtv;
        float dtx = dtv * xcv;
        dtvg[(size_t)row * 256 + d] = dtv;

        float Bt[16] __attribute__((aligned(16)));
        #pragma unroll
        for (int qq = 0; qq < 4; ++qq)
            *(float4*)&Bt[qq * 4] = *(const float4*)&xr[8 + qq * 4];

        float dA[16] __attribute__((aligned(16)));
        dA_powers(dtv, A, fast, dA);
        const f32x2* dA2 = (const f32x2*)dA;
        const f32x2* Bt2 = (const f32x2*)Bt;
        f32x2 dtx2 = (f32x2){dtx, dtx};
        #pragma unroll
        for (int j = 0; j < 8; ++j)
            h2[j] = dA2[j] * h2[j] + dtx2 * Bt2[j];
    }

    const float* hf = (const float*)h2;
    const int base = ((b * NCH + chunk) * 256 + d) * 16;
    #pragma unroll
    for (int qq = 0; qq < 4; ++qq)
        *(float4*)&hend[base + qq * 4] = make_float4(hf[qq*4], hf[qq*4+1], hf[qq*4+2], hf[qq*4+3]);
    dtsg[(b * NCH + chunk) * 256 + d] = dtsum;
}

// ---------------------------------------------------------------------------
// Scan pass 2: sequential combine with P(c) = exp(dtsum(c)*A[n]) computed
// on the fly; hx: hend -> hin in-place. 8-deep prefetch. grid 128, block 256
// ---------------------------------------------------------------------------
__global__ __launch_bounds__(256) void k7_combine(
    const float* __restrict__ dtsg, const float* __restrict__ A_log,
    float* __restrict__ hx)
{
    const int idx = blockIdx.x * 256 + threadIdx.x;   // b*4096 + d*16 + n
    const int b = idx >> 12;
    const int rem = idx & 4095;
    const int d = rem >> 4, n = rem & 15;
    const float An = -__expf(A_log[d * 16 + n]);
    const int base = b * NCH * 4096 + rem;            // hx index, +4096/chunk
    const int sbase = b * NCH * 256 + d;              // dtsg index, +256/chunk
    float h = 0.f;
    float Sb[8], Eb[8];
    #pragma unroll
    for (int j = 0; j < 8; ++j) {
        Sb[j] = dtsg[sbase + j * 256];
        Eb[j] = hx[base + j * 4096];
    }
    for (int g = 0; g < NCH / 8; ++g) {
        const int o  = base + g * 32768;
        const int so = sbase + g * 2048;
        float Sn[8] = {0,0,0,0,0,0,0,0}, En[8] = {0,0,0,0,0,0,0,0};
        if (g < NCH / 8 - 1) {
            #pragma unroll
            for (int j = 0; j < 8; ++j) {
                Sn[j] = dtsg[so + 2048 + j * 256];
                En[j] = hx[o + 32768 + j * 4096];
            }
        }
        #pragma unroll
        for (int j = 0; j < 8; ++j) {
            hx[o + j * 4096] = h;
            float P = __expf(Sb[j] * An);
            h = fmaf(P, h, Eb[j]);
        }
        #pragma unroll
        for (int j = 0; j < 8; ++j) { Sb[j] = Sn[j]; Eb[j] = En[j]; }
    }
}

// ---------------------------------------------------------------------------
// Scan pass 3: replay with h_in using stored dtv (dtx = dtv*xc recomputed);
// y -> ybf (bf16). grid (NCH, BATCH), block 256
// ---------------------------------------------------------------------------
__global__ __launch_bounds__(256) void k8_scan2(
    const unsigned short* __restrict__ xcbf, const float* __restrict__ xdbl,
    const float* __restrict__ dtvg, const float* __restrict__ A_log,
    const float* __restrict__ Dvec, const float* __restrict__ hin,
    const float* __restrict__ zsilu, unsigned short* __restrict__ ybf)
{
    __shared__ float xd[TCH * 40];
    const int d = threadIdx.x;
    const int chunk = blockIdx.x;
    const int b = blockIdx.y;
    const int t0 = b * LSEQ + chunk * TCH;

    {
        const float4* src = (const float4*)&xdbl[t0 * 40];
        if (d < 256) ((float4*)xd)[d] = src[d];
        int i2 = d + 256;
        if (i2 < 320) ((float4*)xd)[i2] = src[i2];
    }

    float A[16];
    #pragma unroll
    for (int qq = 0; qq < 4; ++qq) {
        float4 al = *(const float4*)&A_log[d * 16 + qq * 4];
        A[qq*4+0] = -__expf(al.x); A[qq*4+1] = -__expf(al.y);
        A[qq*4+2] = -__expf(al.z); A[qq*4+3] = -__expf(al.w);
    }
    bool fast = true;
    #pragma unroll
    for (int n = 1; n < 16; ++n)
        fast = fast && (fabsf(A[n] - (n + 1) * A[0]) <= 1e-4f * fabsf(A[n]) + 1e-7f);

    const float Dd = Dvec[d];

    f32x2 h2[8];
    const int hbase = ((b * NCH + chunk) * 256 + d) * 16;
    {
        float hf[16];
        #pragma unroll
        for (int qq = 0; qq < 4; ++qq) {
            float4 hv = *(const float4*)&hin[hbase + qq * 4];
            hf[qq*4+0] = hv.x; hf[qq*4+1] = hv.y; hf[qq*4+2] = hv.z; hf[qq*4+3] = hv.w;
        }
        #pragma unroll
        for (int j = 0; j < 8; ++j) h2[j] = (f32x2){hf[2*j], hf[2*j+1]};
    }
    __syncthreads();

    #pragma unroll 2
    for (int tt = 0; tt < TCH; ++tt) {
        const int row = t0 + tt;
        const size_t gi = (size_t)row * 256 + d;
        float dtv = dtvg[gi];
        float xcv = bf2f(xcbf[gi]);
        float dtx = dtv * xcv;

        const float* xr = &xd[tt * 40];
        float Bt[16] __attribute__((aligned(16)));
        float Ct[16] __attribute__((aligned(16)));
        #pragma unroll
        for (int qq = 0; qq < 4; ++qq) {
            *(float4*)&Bt[qq * 4] = *(const float4*)&xr[8 + qq * 4];
            *(float4*)&Ct[qq * 4] = *(const float4*)&xr[24 + qq * 4];
        }

        float dA[16] __attribute__((aligned(16)));
        dA_powers(dtv, A, fast, dA);
        const f32x2* dA2 = (const f32x2*)dA;
        const f32x2* Bt2 = (const f32x2*)Bt;
        const f32x2* Ct2 = (const f32x2*)Ct;
        f32x2 dtx2 = (f32x2){dtx, dtx};
        f32x2 yv2 = (f32x2){0.f, 0.f};
        #pragma unroll
        for (int j = 0; j < 8; ++j) {
            h2[j] = dA2[j] * h2[j] + dtx2 * Bt2[j];
            yv2 = yv2 + h2[j] * Ct2[j];
        }
        float yv = yv2.x + yv2.y;
        yv = fmaf(Dd, xcv, yv);
        ybf[gi] = f2bf(yv * zsilu[gi]);
    }
}

// ---------------------------------------------------------------------------
// K9 (MFMA bf16): out_bf[b,c,l] = bf16( sum_k y[b,l,k] * W_out[k,c] ).
// Fused GN partial sums in fp32 (atomics into part). grid 256, block 256
// ---------------------------------------------------------------------------
__global__ __launch_bounds__(256) void k9_gemm_out(
    const unsigned short* __restrict__ ybf, const unsigned short* __restrict__ wtout,
    unsigned short* __restrict__ out_bf, float* __restrict__ part)
{
    __shared__ __align__(16) unsigned short Abf[128 * LSTR];   // rows = c
    __shared__ __align__(16) unsigned short Bbf[128 * LSTR];   // rows = l
    const int tid = threadIdx.x;
    const int R0 = blockIdx.x * 128;
    const int b  = R0 >> 12;
    const int l0 = R0 & 4095;

    const int w    = tid >> 6;
    const int lane = tid & 63;
    const int lm   = lane & 15;
    const int q    = lane >> 4;
    const int mbase = (w & 1) * 64;           // c-quadrant
    const int nbase = (w >> 1) * 64;          // l-quadrant

    f32x4 acc[4][4];
    #pragma unroll
    for (int i = 0; i < 4; ++i)
        #pragma unroll
        for (int j = 0; j < 4; ++j) acc[i][j] = (f32x4){0.f, 0.f, 0.f, 0.f};

    for (int kc = 0; kc < 256; kc += 64) {
        __syncthreads();
        #pragma unroll
        for (int it = 0; it < 4; ++it) {
            int slot = tid + it * 256;        // 128 rows x 8 segs
            int r = slot >> 3, seg = slot & 7;
            short8 va = *(const short8*)&wtout[(size_t)r * 256 + kc + seg * 8];
            *(short8*)&Abf[r * LSTR + seg * 8] = va;
            short8 vb = *(const short8*)&ybf[(size_t)(R0 + r) * 256 + kc + seg * 8];
            *(short8*)&Bbf[r * LSTR + seg * 8] = vb;
        }
        __syncthreads();
        #pragma unroll
        for (int kt = 0; kt < 2; ++kt) {
            short8 af[4], bfr[4];
            #pragma unroll
            for (int mt = 0; mt < 4; ++mt)
                af[mt] = *(const short8*)&Abf[(mbase + mt * 16 + lm) * LSTR + kt * 32 + q * 8];
            #pragma unroll
            for (int nt = 0; nt < 4; ++nt)
                bfr[nt] = *(const short8*)&Bbf[(nbase + nt * 16 + lm) * LSTR + kt * 32 + q * 8];
            #pragma unroll
            for (int mt = 0; mt < 4; ++mt)
                #pragma unroll
                for (int nt = 0; nt < 4; ++nt)
                    acc[mt][nt] = __builtin_amdgcn_mfma_f32_16x16x32_bf16(
                        af[mt], bfr[nt], acc[mt][nt], 0, 0, 0);
        }
    }

    #pragma unroll
    for (int mt = 0; mt < 4; ++mt) {
        #pragma unroll
        for (int r = 0; r < 4; ++r) {
            int c = mbase + mt * 16 + q * 4 + r;
            long base = (long)(b * 128 + c) * 4096 + l0;
            #pragma unroll
            for (int nt = 0; nt < 4; ++nt)
                out_bf[base + nbase + nt * 16 + lm] = f2bf(acc[mt][nt][r]);
        }
    }

    // fused GroupNorm partial sums (fp32 from accumulators)
    float s0 = 0.f, q0 = 0.f, s1 = 0.f, q1 = 0.f;
    #pragma unroll
    for (int mt = 0; mt < 4; ++mt)
        #pragma unroll
        for (int nt = 0; nt < 4; ++nt)
            #pragma unroll
            for (int r = 0; r < 4; ++r) {
                float v = acc[mt][nt][r];
                if (mt < 2) { s0 += v; q0 += v * v; }
                else        { s1 += v; q1 += v * v; }
            }
    #pragma unroll
    for (int off = 32; off > 0; off >>= 1) {
        s0 += __shfl_down(s0, off, 64);
        q0 += __shfl_down(q0, off, 64);
        s1 += __shfl_down(s1, off, 64);
        q1 += __shfl_down(q1, off, 64);
    }
    if (lane == 0) {
        int g0 = mbase >> 5;
        atomicAdd(&part[(b * 4 + g0) * 2],     s0);
        atomicAdd(&part[(b * 4 + g0) * 2 + 1], q0);
        atomicAdd(&part[(b * 4 + g0 + 1) * 2],     s1);
        atomicAdd(&part[(b * 4 + g0 + 1) * 2 + 1], q1);
    }
}

// K10c: apply GN + silu + residual (stat computed inline from part; out_mm
// read as bf16). grid 4096, block 256
__global__ __launch_bounds__(256) void k10c_apply(
    const unsigned short* __restrict__ out_bf, const float* __restrict__ part,
    const float* __restrict__ gamma, const float* __restrict__ beta,
    const float* __restrict__ x_hsi, float* __restrict__ out)
{
    __shared__ float sstat[64];
    if (threadIdx.x < 32) {
        float S = part[threadIdx.x * 2];
        float Q = part[threadIdx.x * 2 + 1];
        const float inv_n = 1.0f / 131072.0f;
        float mean = S * inv_n;
        float var  = Q * inv_n - mean * mean;
        sstat[threadIdx.x * 2]     = mean;
        sstat[threadIdx.x * 2 + 1] = rsqrtf(var + 1e-5f);
    }
    __syncthreads();
    const int idx4 = blockIdx.x * 256 + threadIdx.x;
    const int flat = idx4 * 4;
    const int c = (flat >> 12) & 127;
    const int b = flat >> 19;
    const int g = c >> 5;
    const float mean = sstat[(b * 4 + g) * 2];
    const float inv  = sstat[(b * 4 + g) * 2 + 1];
    const float ga = gamma[c], be = beta[c];
    ushort4 u = *(const ushort4*)&out_bf[flat];
    float4 r = *(const float4*)&x_hsi[flat];
    float vv[4] = {bf2f(u.x), bf2f(u.y), bf2f(u.z), bf2f(u.w)};
    float rr[4] = {r.x, r.y, r.z, r.w};
    float o[4];
    #pragma unroll
    for (int qq = 0; qq < 4; ++qq) {
        float xn = (vv[qq] - mean) * inv;
        float gv = xn * ga + be;
        o[qq] = silu_fast(gv) + rr[qq];
    }
    *(float4*)&out[flat] = make_float4(o[0], o[1], o[2], o[3]);
}

// ---------------------------------------------------------------------------
extern "C" void kernel_launch(void* const* d_in, const int* in_sizes, int n_in,
                              void* d_out, int out_size, void* d_ws, size_t ws_size,
                              hipStream_t stream)
{
    const float* x_hsi  = (const float*)d_in[0];
    const float* W_in   = (const float*)d_in[1];
    const float* conv_w = (const float*)d_in[2];
    const float* conv_b = (const float*)d_in[3];
    const float* W_x    = (const float*)d_in[4];
    const float* W_dt   = (const float*)d_in[5];
    const float* b_dt   = (const float*)d_in[6];
    const float* A_log  = (const float*)d_in[7];
    const float* Dv     = (const float*)d_in[8];
    const float* W_out  = (const float*)d_in[9];
    const float* gnw    = (const float*)d_in[10];
    const float* gnb    = (const float*)d_in[11];

    float* ws = (float*)d_ws;
    float* xh_raw = ws + 0;            // 8,388,608 f (ybf aliases after k4)
    float* zsilu  = ws + 8388608;      // 8,388,608 f
    float* xdbl   = ws + 16777216;     // 327,680 f
    float* hx     = ws + 17104896;     // 4,194,304 f (NCH=128)  hend->hin in-place
    float* dtvg   = ws + 21299200;     // 8,388,608 f
    float* dtsg   = ws + 29687808;     // 262,144 f
    unsigned short* xcbf = (unsigned short*)(ws + 29949952);  // 8,388,608 us
    unsigned short* out_bf = (unsigned short*)(ws + 34144256); // 4,194,304 us
    float* part   = ws + 36241408;     // 64 f
    unsigned short* wtin  = (unsigned short*)(ws + 36241536); // 65,536 us
    unsigned short* wtout = (unsigned short*)(ws + 36274304); // 32,768 us
    unsigned short* ybf   = (unsigned short*)xh_raw;          // alias: xh dead after k4
    float* outp   = (float*)d_out;

    k0_setup<<<25, 256, 0, stream>>>(W_in, W_out, wtin, wtout, part);
    k1_gemm_in<<<dim3(256, 2), 512, 0, stream>>>(x_hsi, wtin, xh_raw, zsilu);
    k4_xdbl<<<256, 256, 0, stream>>>(xh_raw, conv_w, conv_b, W_x, xdbl, xcbf);
    k6_scan1<<<dim3(NCH, BATCH), 256, 0, stream>>>(xcbf, xdbl, W_dt, b_dt, A_log,
                                                   hx, dtsg, dtvg);
    k7_combine<<<128, 256, 0, stream>>>(dtsg, A_log, hx);
    k8_scan2<<<dim3(NCH, BATCH), 256, 0, stream>>>(xcbf, xdbl, dtvg,
                                                   A_log, Dv, hx, zsilu, ybf);
    k9_gemm_out<<<256, 256, 0, stream>>>(ybf, wtout, out_bf, part);
    k10c_apply<<<4096, 256, 0, stream>>>(out_bf, part, gnw, gnb, x_hsi, outp);
}

// Round 12
// 232.929 us; speedup vs baseline: 1.0607x; 1.0155x over previous
//
#include <hip/hip_runtime.h>
#include <hip/hip_bf16.h>
#include <hip/hip_fp16.h>
#include <math.h>

// Problem constants
#define BATCH   8
#define LSEQ    4096      // 64*64
#define CMODEL  128
#define DIN     256
#define NSTATE  16
#define RRANK   8
#define NCH     128       // chunks per sequence
#define TCH     32        // timesteps per chunk (NCH*TCH == LSEQ)

typedef __attribute__((ext_vector_type(8))) short short8;
typedef __attribute__((ext_vector_type(4))) float f32x4;
typedef __attribute__((ext_vector_type(2))) float f32x2;

__device__ __forceinline__ float sigmoid_fast(float x) {
    return __builtin_amdgcn_rcpf(1.0f + __expf(-x));
}
__device__ __forceinline__ float silu_fast(float x) { return x * sigmoid_fast(x); }
__device__ __forceinline__ float softplus_fast(float x) {
    return fmaxf(x, 0.0f) + __logf(1.0f + __expf(-fabsf(x)));
}
__device__ __forceinline__ float bf2f(unsigned short u) {
    return __uint_as_float(((unsigned)u) << 16);
}
// packed fp32x2 -> bf16x2 (v_cvt_pk_bf16_f32); a -> low, b -> high
__device__ __forceinline__ unsigned pk2bf(float a, float b) {
    __hip_bfloat162 t = __float22bfloat162_rn(make_float2(a, b));
    unsigned r;
    __builtin_memcpy(&r, &t, 4);
    return r;
}
__device__ __forceinline__ unsigned short f2bf1(float v) {   // 1-op scalar cvt
    return (unsigned short)pk2bf(v, v);
}
// bf16x2 (packed dword) -> f32x2
__device__ __forceinline__ f32x2 up2(unsigned w) {
    return (f32x2){ __uint_as_float(w << 16), __uint_as_float(w & 0xffff0000u) };
}

// dA2[j] = {exp(dtv*A[2j]), exp(dtv*A[2j+1])}; fast path via packed mul chain.
__device__ __forceinline__ void dA_powers2(float dtv, const float* A, bool fast,
                                           f32x2* dA2)
{
    if (fast) {
        float e1 = __expf(dtv * A[0]);
        float e2 = e1 * e1;
        dA2[0] = (f32x2){e1, e2};
        f32x2 e2s = (f32x2){e2, e2};
        #pragma unroll
        for (int j = 1; j < 8; ++j) dA2[j] = dA2[j-1] * e2s;
    } else {
        #pragma unroll
        for (int j = 0; j < 8; ++j)
            dA2[j] = (f32x2){__expf(dtv * A[2*j]), __expf(dtv * A[2*j+1])};
    }
}

#define LSTR 72   // LDS row stride (bf16 units): 64 data + 8 pad; 2-way max = free

// ---------------------------------------------------------------------------
// K0: weight transposes (tiny) + part zero. grid 25, block 256
// ---------------------------------------------------------------------------
__device__ __forceinline__ void tr64_bf(const float* __restrict__ src, int lds,
                                        int r0, int c0,
                                        unsigned short* __restrict__ dst, int ldd)
{
    __shared__ float ts[64][65];
    const int tid = threadIdx.x;
    #pragma unroll
    for (int it = 0; it < 4; ++it) {
        int slot = tid + it * 256;
        int i = slot >> 4, j4 = slot & 15;
        float4 v = *(const float4*)&src[(size_t)(r0 + i) * lds + c0 + j4 * 4];
        ts[i][j4*4+0] = v.x; ts[i][j4*4+1] = v.y;
        ts[i][j4*4+2] = v.z; ts[i][j4*4+3] = v.w;
    }
    __syncthreads();
    #pragma unroll
    for (int it = 0; it < 4; ++it) {
        int slot = tid + it * 256;
        int row = slot >> 4, c4 = slot & 15;
        unsigned p0 = pk2bf(ts[c4*4+0][row], ts[c4*4+1][row]);
        unsigned p1 = pk2bf(ts[c4*4+2][row], ts[c4*4+3][row]);
        unsigned long long u = (unsigned long long)p0 | ((unsigned long long)p1 << 32);
        *(unsigned long long*)&dst[(size_t)(c0 + row) * ldd + r0 + c4 * 4] = u;
    }
}

__global__ __launch_bounds__(256) void k0_setup(
    const float* __restrict__ W_in, const float* __restrict__ W_out,
    unsigned short* __restrict__ wtin, unsigned short* __restrict__ wtout,
    float* __restrict__ part)
{
    const int bid = blockIdx.x;
    if (bid < 16) {
        int ct = bid >> 3, jt = bid & 7;
        tr64_bf(W_in, 512, ct * 64, jt * 64, wtin, 128);
    } else if (bid < 24) {
        int t3 = bid - 16;
        int kt = t3 >> 1, ct = t3 & 1;
        tr64_bf(W_out, 128, kt * 64, ct * 64, wtout, 256);
    } else {
        if (threadIdx.x < 64) part[threadIdx.x] = 0.0f;
    }
}

// ---------------------------------------------------------------------------
// K1 (MFMA bf16): xz = x @ W_in. 128(l) x 256(j) tile, 8 waves, K=128 in
// chunks of 64. Outputs bf16 xhbf / zbf. grid (256, 2), block 512
// ---------------------------------------------------------------------------
__global__ __launch_bounds__(512) void k1_gemm_in(
    const float* __restrict__ x_hsi, const unsigned short* __restrict__ wtin,
    unsigned short* __restrict__ xhbf, unsigned short* __restrict__ zbf)
{
    __shared__ __align__(16) unsigned short Abf[128 * LSTR];   // rows = l
    __shared__ __align__(16) unsigned short Bbf[256 * LSTR];   // rows = j
    const int tid = threadIdx.x;
    const int R0  = blockIdx.x * 128;         // global row (b*L + l)
    const int b   = R0 >> 12;
    const int l0  = R0 & 4095;
    const int jbase = blockIdx.y * 256;

    const int w    = tid >> 6;                // 0..7
    const int lane = tid & 63;
    const int lm   = lane & 15;
    const int q    = lane >> 4;
    const int mbase = (w & 1) * 64;           // l-quadrant
    const int nbase = (w >> 1) * 64;          // j-quadrant (0..192)

    f32x4 acc[4][4];
    #pragma unroll
    for (int i = 0; i < 4; ++i)
        #pragma unroll
        for (int j = 0; j < 4; ++j) acc[i][j] = (f32x4){0.f, 0.f, 0.f, 0.f};

    const int cq = tid & 15;                  // c-quad within chunk (16*4=64)
    const int lq = tid >> 4;                  // l-quad (32*4=128)

    for (int kc = 0; kc < 128; kc += 64) {
        __syncthreads();
        // stage A: x[c][l] -> Abf[l][c_local] (transpose + packed cvt)
        {
            float v[4][4];
            #pragma unroll
            for (int t = 0; t < 4; ++t) {
                float4 f = *(const float4*)&x_hsi[((b * 128 + kc + cq * 4 + t) << 12) + l0 + lq * 4];
                v[t][0] = f.x; v[t][1] = f.y; v[t][2] = f.z; v[t][3] = f.w;
            }
            #pragma unroll
            for (int i = 0; i < 4; ++i) {
                unsigned p0 = pk2bf(v[0][i], v[1][i]);
                unsigned p1 = pk2bf(v[2][i], v[3][i]);
                unsigned long long u = (unsigned long long)p0 | ((unsigned long long)p1 << 32);
                *(unsigned long long*)&Abf[(lq * 4 + i) * LSTR + cq * 4] = u;
            }
        }
        // stage B: direct bf16 copy from wtin (256 rows x 8 segs)
        #pragma unroll
        for (int it = 0; it < 4; ++it) {
            int slot = tid + it * 512;
            int r = slot >> 3, seg = slot & 7;
            short8 vb = *(const short8*)&wtin[(size_t)(jbase + r) * 128 + kc + seg * 8];
            *(short8*)&Bbf[r * LSTR + seg * 8] = vb;
        }
        __syncthreads();
        #pragma unroll
        for (int kt = 0; kt < 2; ++kt) {
            short8 af[4], bfr[4];
            #pragma unroll
            for (int mt = 0; mt < 4; ++mt)
                af[mt] = *(const short8*)&Abf[(mbase + mt * 16 + lm) * LSTR + kt * 32 + q * 8];
            #pragma unroll
            for (int nt = 0; nt < 4; ++nt)
                bfr[nt] = *(const short8*)&Bbf[(nbase + nt * 16 + lm) * LSTR + kt * 32 + q * 8];
            #pragma unroll
            for (int mt = 0; mt < 4; ++mt)
                #pragma unroll
                for (int nt = 0; nt < 4; ++nt)
                    acc[mt][nt] = __builtin_amdgcn_mfma_f32_16x16x32_bf16(
                        af[mt], bfr[nt], acc[mt][nt], 0, 0, 0);
        }
    }

    const bool is_xh = (jbase == 0);
    #pragma unroll
    for (int mt = 0; mt < 4; ++mt) {
        #pragma unroll
        for (int r = 0; r < 4; ++r) {
            int row = R0 + mbase + mt * 16 + q * 4 + r;
            #pragma unroll
            for (int nt = 0; nt < 4; ++nt) {
                int col = nbase + nt * 16 + lm;     // 0..255
                float val = acc[mt][nt][r];
                if (is_xh) xhbf[row * 256 + col] = f2bf1(val);
                else       zbf[row * 256 + col]  = f2bf1(silu_fast(val));
            }
        }
    }
}

// ---------------------------------------------------------------------------
// K4: xdbl = conv_silu(xh) @ W_x tiled GEMM (fp32) + emit xcbf (bf16 conv out).
// xh read as bf16. grid 256, block 256
// ---------------------------------------------------------------------------
__global__ __launch_bounds__(256) void k4_xdbl(
    const unsigned short* __restrict__ xhbf, const float* __restrict__ conv_w,
    const float* __restrict__ conv_b, const float* __restrict__ W_x,
    float* __restrict__ xdbl, unsigned short* __restrict__ xcbf)
{
    __shared__ float xcs[128][68];
    __shared__ float wxs[64 * 40];
    __shared__ float cw0[256], cw1[256], cbs[256];
    const int tid = threadIdx.x;
    cw0[tid] = conv_w[2 * tid];
    cw1[tid] = conv_w[2 * tid + 1];
    cbs[tid] = conv_b[tid];

    const int R0 = blockIdx.x * 128;
    const int tc = tid & 7;
    const int tr = tid >> 3;

    float acc[4][5];
    #pragma unroll
    for (int i = 0; i < 4; ++i)
        #pragma unroll
        for (int j = 0; j < 5; ++j) acc[i][j] = 0.0f;

    for (int kc = 0; kc < 256; kc += 64) {
        __syncthreads();
        #pragma unroll
        for (int it = 0; it < 3; ++it) {
            int i4 = tid + it * 256;
            if (i4 < 640) ((float4*)wxs)[i4] = ((const float4*)&W_x[kc * 40])[i4];
        }
        #pragma unroll
        for (int it = 0; it < 8; ++it) {
            int idx = tid + it * 256;
            int r = idx >> 4, qq = idx & 15;
            int row = R0 + r;
            ushort4 cu = *(const ushort4*)&xhbf[(size_t)row * 256 + kc + qq * 4];
            float cur[4] = {bf2f(cu.x), bf2f(cu.y), bf2f(cu.z), bf2f(cu.w)};
            float pv[4] = {0.f, 0.f, 0.f, 0.f};
            if ((row & 4095) != 0) {
                ushort4 pu = *(const ushort4*)&xhbf[(size_t)(row - 1) * 256 + kc + qq * 4];
                pv[0] = bf2f(pu.x); pv[1] = bf2f(pu.y);
                pv[2] = bf2f(pu.z); pv[3] = bf2f(pu.w);
            }
            int d = kc + qq * 4;
            float o[4];
            #pragma unroll
            for (int e = 0; e < 4; ++e)
                o[e] = silu_fast(pv[e] * cw0[d+e] + cur[e] * cw1[d+e] + cbs[d+e]);
            *(float4*)&xcs[r][qq * 4] = make_float4(o[0], o[1], o[2], o[3]);
            unsigned p0 = pk2bf(o[0], o[1]), p1 = pk2bf(o[2], o[3]);
            unsigned long long u = (unsigned long long)p0 | ((unsigned long long)p1 << 32);
            *(unsigned long long*)&xcbf[(size_t)row * 256 + d] = u;
        }
        __syncthreads();
        #pragma unroll 2
        for (int k = 0; k < 64; ++k) {
            float wv[5];
            #pragma unroll
            for (int j = 0; j < 5; ++j) wv[j] = wxs[k * 40 + tc * 5 + j];
            #pragma unroll
            for (int i = 0; i < 4; ++i) {
                float a = xcs[tr * 4 + i][k];
                #pragma unroll
                for (int j = 0; j < 5; ++j) acc[i][j] = fmaf(a, wv[j], acc[i][j]);
            }
        }
    }
    #pragma unroll
    for (int i = 0; i < 4; ++i) {
        int row = R0 + tr * 4 + i;
        #pragma unroll
        for (int j = 0; j < 5; ++j) xdbl[row * 40 + tc * 5 + j] = acc[i][j];
    }
}

// ---------------------------------------------------------------------------
// Scan pass 1: local h (h_in=0); emits dtv (fp16) per step + dtsum per chunk.
// LDS row (64 B): dtlow fp32[8] | B bf16[16]. grid (NCH, BATCH), block 256
// ---------------------------------------------------------------------------
__global__ __launch_bounds__(256) void k6_scan1(
    const unsigned short* __restrict__ xcbf, const float* __restrict__ xdbl,
    const float* __restrict__ W_dt, const float* __restrict__ b_dt,
    const float* __restrict__ A_log,
    float* __restrict__ hend, float* __restrict__ dtsg,
    __half* __restrict__ dtvh)
{
    __shared__ __align__(16) unsigned char xdb[TCH * 64];
    const int d = threadIdx.x;
    const int chunk = blockIdx.x;
    const int b = blockIdx.y;
    const int t0 = b * LSEQ + chunk * TCH;

    {
        int row = d >> 3, seg = d & 7;
        const float4* src = (const float4*)&xdbl[(size_t)(t0 + row) * 40];
        if (seg < 2) {
            *(float4*)&xdb[row * 64 + seg * 16] = src[seg];
        } else if (seg < 6) {
            float4 f = src[seg];                  // B[ (seg-2)*4 .. +3 ]
            unsigned p0 = pk2bf(f.x, f.y), p1 = pk2bf(f.z, f.w);
            *(uint2*)&xdb[row * 64 + 32 + (seg - 2) * 8] = make_uint2(p0, p1);
        }
    }

    float A[16];
    #pragma unroll
    for (int qq = 0; qq < 4; ++qq) {
        float4 al = *(const float4*)&A_log[d * 16 + qq * 4];
        A[qq*4+0] = -__expf(al.x); A[qq*4+1] = -__expf(al.y);
        A[qq*4+2] = -__expf(al.z); A[qq*4+3] = -__expf(al.w);
    }
    bool fast = true;
    #pragma unroll
    for (int n = 1; n < 16; ++n)
        fast = fast && (fabsf(A[n] - (n + 1) * A[0]) <= 1e-4f * fabsf(A[n]) + 1e-7f);

    float wdt[8];
    #pragma unroll
    for (int r = 0; r < 8; ++r) wdt[r] = W_dt[r * 256 + d];
    const float bdt = b_dt[d];

    f32x2 h2[8];
    #pragma unroll
    for (int j = 0; j < 8; ++j) h2[j] = (f32x2){0.f, 0.f};
    float dtsum = 0.f;
    __syncthreads();

    #pragma unroll 2
    for (int tt = 0; tt < TCH; ++tt) {
        const int row = t0 + tt;
        float xcv = bf2f(xcbf[(size_t)row * 256 + d]);

        const unsigned char* xr = &xdb[tt * 64];
        float dl[8];
        *(float4*)&dl[0] = *(const float4*)xr;
        *(float4*)&dl[4] = *(const float4*)(xr + 16);
        float dtr = bdt;
        #pragma unroll
        for (int r = 0; r < 8; ++r) dtr = fmaf(dl[r], wdt[r], dtr);
        float dtv = softplus_fast(dtr);
        dtsum += dtv;
        float dtx = dtv * xcv;
        dtvh[(size_t)row * 256 + d] = __float2half(dtv);

        uint4 bu0 = *(const uint4*)(xr + 32);
        uint4 bu1 = *(const uint4*)(xr + 48);
        f32x2 Bt2[8] = {up2(bu0.x), up2(bu0.y), up2(bu0.z), up2(bu0.w),
                        up2(bu1.x), up2(bu1.y), up2(bu1.z), up2(bu1.w)};

        f32x2 dA2[8];
        dA_powers2(dtv, A, fast, dA2);
        f32x2 dtx2 = (f32x2){dtx, dtx};
        #pragma unroll
        for (int j = 0; j < 8; ++j)
            h2[j] = dA2[j] * h2[j] + dtx2 * Bt2[j];
    }

    const float* hf = (const float*)h2;
    const int base = ((b * NCH + chunk) * 256 + d) * 16;
    #pragma unroll
    for (int qq = 0; qq < 4; ++qq)
        *(float4*)&hend[base + qq * 4] = make_float4(hf[qq*4], hf[qq*4+1], hf[qq*4+2], hf[qq*4+3]);
    dtsg[(b * NCH + chunk) * 256 + d] = dtsum;
}

// ---------------------------------------------------------------------------
// Scan pass 2: sequential combine with P(c) = exp(dtsum(c)*A[n]) on the fly;
// hx: hend -> hin in-place. 8-deep prefetch. grid 128, block 256
// ---------------------------------------------------------------------------
__global__ __launch_bounds__(256) void k7_combine(
    const float* __restrict__ dtsg, const float* __restrict__ A_log,
    float* __restrict__ hx)
{
    const int idx = blockIdx.x * 256 + threadIdx.x;   // b*4096 + d*16 + n
    const int b = idx >> 12;
    const int rem = idx & 4095;
    const int d = rem >> 4, n = rem & 15;
    const float An = -__expf(A_log[d * 16 + n]);
    const int base = b * NCH * 4096 + rem;            // hx index, +4096/chunk
    const int sbase = b * NCH * 256 + d;              // dtsg index, +256/chunk
    float h = 0.f;
    float Sb[8], Eb[8];
    #pragma unroll
    for (int j = 0; j < 8; ++j) {
        Sb[j] = dtsg[sbase + j * 256];
        Eb[j] = hx[base + j * 4096];
    }
    for (int g = 0; g < NCH / 8; ++g) {
        const int o  = base + g * 32768;
        const int so = sbase + g * 2048;
        float Sn[8] = {0,0,0,0,0,0,0,0}, En[8] = {0,0,0,0,0,0,0,0};
        if (g < NCH / 8 - 1) {
            #pragma unroll
            for (int j = 0; j < 8; ++j) {
                Sn[j] = dtsg[so + 2048 + j * 256];
                En[j] = hx[o + 32768 + j * 4096];
            }
        }
        #pragma unroll
        for (int j = 0; j < 8; ++j) {
            hx[o + j * 4096] = h;
            float P = __expf(Sb[j] * An);
            h = fmaf(P, h, Eb[j]);
        }
        #pragma unroll
        for (int j = 0; j < 8; ++j) { Sb[j] = Sn[j]; Eb[j] = En[j]; }
    }
}

// ---------------------------------------------------------------------------
// Scan pass 3: replay with h_in using stored dtv (fp16); y -> ybf (bf16).
// LDS row (64 B): B bf16[16] | C bf16[16]. grid (NCH, BATCH), block 256
// ---------------------------------------------------------------------------
__global__ __launch_bounds__(256) void k8_scan2(
    const unsigned short* __restrict__ xcbf, const float* __restrict__ xdbl,
    const __half* __restrict__ dtvh, const float* __restrict__ A_log,
    const float* __restrict__ Dvec, const float* __restrict__ hin,
    const unsigned short* __restrict__ zbf, unsigned short* __restrict__ ybf)
{
    __shared__ __align__(16) unsigned char xdb[TCH * 64];
    const int d = threadIdx.x;
    const int chunk = blockIdx.x;
    const int b = blockIdx.y;
    const int t0 = b * LSEQ + chunk * TCH;

    {
        int row = d >> 3, seg = d & 7;
        float4 f = *(const float4*)&xdbl[(size_t)(t0 + row) * 40 + 8 + seg * 4];
        unsigned p0 = pk2bf(f.x, f.y), p1 = pk2bf(f.z, f.w);
        *(uint2*)&xdb[row * 64 + seg * 8] = make_uint2(p0, p1);
    }

    float A[16];
    #pragma unroll
    for (int qq = 0; qq < 4; ++qq) {
        float4 al = *(const float4*)&A_log[d * 16 + qq * 4];
        A[qq*4+0] = -__expf(al.x); A[qq*4+1] = -__expf(al.y);
        A[qq*4+2] = -__expf(al.z); A[qq*4+3] = -__expf(al.w);
    }
    bool fast = true;
    #pragma unroll
    for (int n = 1; n < 16; ++n)
        fast = fast && (fabsf(A[n] - (n + 1) * A[0]) <= 1e-4f * fabsf(A[n]) + 1e-7f);

    const float Dd = Dvec[d];

    f32x2 h2[8];
    const int hbase = ((b * NCH + chunk) * 256 + d) * 16;
    {
        float hf[16];
        #pragma unroll
        for (int qq = 0; qq < 4; ++qq) {
            float4 hv = *(const float4*)&hin[hbase + qq * 4];
            hf[qq*4+0] = hv.x; hf[qq*4+1] = hv.y; hf[qq*4+2] = hv.z; hf[qq*4+3] = hv.w;
        }
        #pragma unroll
        for (int j = 0; j < 8; ++j) h2[j] = (f32x2){hf[2*j], hf[2*j+1]};
    }
    __syncthreads();

    #pragma unroll 2
    for (int tt = 0; tt < TCH; ++tt) {
        const int row = t0 + tt;
        const size_t gi = (size_t)row * 256 + d;
        float dtv = __half2float(dtvh[gi]);
        float xcv = bf2f(xcbf[gi]);
        float dtx = dtv * xcv;

        const unsigned char* xr = &xdb[tt * 64];
        uint4 bu0 = *(const uint4*)(xr + 0);
        uint4 bu1 = *(const uint4*)(xr + 16);
        uint4 cu0 = *(const uint4*)(xr + 32);
        uint4 cu1 = *(const uint4*)(xr + 48);
        f32x2 Bt2[8] = {up2(bu0.x), up2(bu0.y), up2(bu0.z), up2(bu0.w),
                        up2(bu1.x), up2(bu1.y), up2(bu1.z), up2(bu1.w)};
        f32x2 Ct2[8] = {up2(cu0.x), up2(cu0.y), up2(cu0.z), up2(cu0.w),
                        up2(cu1.x), up2(cu1.y), up2(cu1.z), up2(cu1.w)};

        f32x2 dA2[8];
        dA_powers2(dtv, A, fast, dA2);
        f32x2 dtx2 = (f32x2){dtx, dtx};
        f32x2 yv2 = (f32x2){0.f, 0.f};
        #pragma unroll
        for (int j = 0; j < 8; ++j) {
            h2[j] = dA2[j] * h2[j] + dtx2 * Bt2[j];
            yv2 = yv2 + h2[j] * Ct2[j];
        }
        float yv = yv2.x + yv2.y;
        yv = fmaf(Dd, xcv, yv);
        ybf[gi] = f2bf1(yv * bf2f(zbf[gi]));
    }
}

// ---------------------------------------------------------------------------
// K9 (MFMA bf16): out_bf[b,c,l] = bf16( sum_k y[b,l,k] * W_out[k,c] ).
// Fused GN partial sums in fp32 (atomics into part). grid 256, block 256
// ---------------------------------------------------------------------------
__global__ __launch_bounds__(256) void k9_gemm_out(
    const unsigned short* __restrict__ ybf, const unsigned short* __restrict__ wtout,
    unsigned short* __restrict__ out_bf, float* __restrict__ part)
{
    __shared__ __align__(16) unsigned short Abf[128 * LSTR];   // rows = c
    __shared__ __align__(16) unsigned short Bbf[128 * LSTR];   // rows = l
    const int tid = threadIdx.x;
    const int R0 = blockIdx.x * 128;
    const int b  = R0 >> 12;
    const int l0 = R0 & 4095;

    const int w    = tid >> 6;
    const int lane = tid & 63;
    const int lm   = lane & 15;
    const int q    = lane >> 4;
    const int mbase = (w & 1) * 64;           // c-quadrant
    const int nbase = (w >> 1) * 64;          // l-quadrant

    f32x4 acc[4][4];
    #pragma unroll
    for (int i = 0; i < 4; ++i)
        #pragma unroll
        for (int j = 0; j < 4; ++j) acc[i][j] = (f32x4){0.f, 0.f, 0.f, 0.f};

    for (int kc = 0; kc < 256; kc += 64) {
        __syncthreads();
        #pragma unroll
        for (int it = 0; it < 4; ++it) {
            int slot = tid + it * 256;        // 128 rows x 8 segs
            int r = slot >> 3, seg = slot & 7;
            short8 va = *(const short8*)&wtout[(size_t)r * 256 + kc + seg * 8];
            *(short8*)&Abf[r * LSTR + seg * 8] = va;
            short8 vb = *(const short8*)&ybf[(size_t)(R0 + r) * 256 + kc + seg * 8];
            *(short8*)&Bbf[r * LSTR + seg * 8] = vb;
        }
        __syncthreads();
        #pragma unroll
        for (int kt = 0; kt < 2; ++kt) {
            short8 af[4], bfr[4];
            #pragma unroll
            for (int mt = 0; mt < 4; ++mt)
                af[mt] = *(const short8*)&Abf[(mbase + mt * 16 + lm) * LSTR + kt * 32 + q * 8];
            #pragma unroll
            for (int nt = 0; nt < 4; ++nt)
                bfr[nt] = *(const short8*)&Bbf[(nbase + nt * 16 + lm) * LSTR + kt * 32 + q * 8];
            #pragma unroll
            for (int mt = 0; mt < 4; ++mt)
                #pragma unroll
                for (int nt = 0; nt < 4; ++nt)
                    acc[mt][nt] = __builtin_amdgcn_mfma_f32_16x16x32_bf16(
                        af[mt], bfr[nt], acc[mt][nt], 0, 0, 0);
        }
    }

    #pragma unroll
    for (int mt = 0; mt < 4; ++mt) {
        #pragma unroll
        for (int r = 0; r < 4; ++r) {
            int c = mbase + mt * 16 + q * 4 + r;
            long base = (long)(b * 128 + c) * 4096 + l0;
            #pragma unroll
            for (int nt = 0; nt < 4; ++nt)
                out_bf[base + nbase + nt * 16 + lm] = f2bf1(acc[mt][nt][r]);
        }
    }

    // fused GroupNorm partial sums (fp32 from accumulators)
    float s0 = 0.f, q0 = 0.f, s1 = 0.f, q1 = 0.f;
    #pragma unroll
    for (int mt = 0; mt < 4; ++mt)
        #pragma unroll
        for (int nt = 0; nt < 4; ++nt)
            #pragma unroll
            for (int r = 0; r < 4; ++r) {
                float v = acc[mt][nt][r];
                if (mt < 2) { s0 += v; q0 += v * v; }
                else        { s1 += v; q1 += v * v; }
            }
    #pragma unroll
    for (int off = 32; off > 0; off >>= 1) {
        s0 += __shfl_down(s0, off, 64);
        q0 += __shfl_down(q0, off, 64);
        s1 += __shfl_down(s1, off, 64);
        q1 += __shfl_down(q1, off, 64);
    }
    if (lane == 0) {
        int g0 = mbase >> 5;
        atomicAdd(&part[(b * 4 + g0) * 2],     s0);
        atomicAdd(&part[(b * 4 + g0) * 2 + 1], q0);
        atomicAdd(&part[(b * 4 + g0 + 1) * 2],     s1);
        atomicAdd(&part[(b * 4 + g0 + 1) * 2 + 1], q1);
    }
}

// K10c: apply GN + silu + residual (stat from part; out_bf bf16).
// grid 4096, block 256
__global__ __launch_bounds__(256) void k10c_apply(
    const unsigned short* __restrict__ out_bf, const float* __restrict__ part,
    const float* __restrict__ gamma, const float* __restrict__ beta,
    const float* __restrict__ x_hsi, float* __restrict__ out)
{
    __shared__ float sstat[64];
    if (threadIdx.x < 32) {
        float S = part[threadIdx.x * 2];
        float Q = part[threadIdx.x * 2 + 1];
        const float inv_n = 1.0f / 131072.0f;
        float mean = S * inv_n;
        float var  = Q * inv_n - mean * mean;
        sstat[threadIdx.x * 2]     = mean;
        sstat[threadIdx.x * 2 + 1] = rsqrtf(var + 1e-5f);
    }
    __syncthreads();
    const int idx4 = blockIdx.x * 256 + threadIdx.x;
    const int flat = idx4 * 4;
    const int c = (flat >> 12) & 127;
    const int b = flat >> 19;
    const int g = c >> 5;
    const float mean = sstat[(b * 4 + g) * 2];
    const float inv  = sstat[(b * 4 + g) * 2 + 1];
    const float ga = gamma[c], be = beta[c];
    ushort4 u = *(const ushort4*)&out_bf[flat];
    float4 r = *(const float4*)&x_hsi[flat];
    float vv[4] = {bf2f(u.x), bf2f(u.y), bf2f(u.z), bf2f(u.w)};
    float rr[4] = {r.x, r.y, r.z, r.w};
    float o[4];
    #pragma unroll
    for (int qq = 0; qq < 4; ++qq) {
        float xn = (vv[qq] - mean) * inv;
        float gv = xn * ga + be;
        o[qq] = silu_fast(gv) + rr[qq];
    }
    *(float4*)&out[flat] = make_float4(o[0], o[1], o[2], o[3]);
}

// ---------------------------------------------------------------------------
extern "C" void kernel_launch(void* const* d_in, const int* in_sizes, int n_in,
                              void* d_out, int out_size, void* d_ws, size_t ws_size,
                              hipStream_t stream)
{
    const float* x_hsi  = (const float*)d_in[0];
    const float* W_in   = (const float*)d_in[1];
    const float* conv_w = (const float*)d_in[2];
    const float* conv_b = (const float*)d_in[3];
    const float* W_x    = (const float*)d_in[4];
    const float* W_dt   = (const float*)d_in[5];
    const float* b_dt   = (const float*)d_in[6];
    const float* A_log  = (const float*)d_in[7];
    const float* Dv     = (const float*)d_in[8];
    const float* W_out  = (const float*)d_in[9];
    const float* gnw    = (const float*)d_in[10];
    const float* gnb    = (const float*)d_in[11];

    float* ws = (float*)d_ws;
    unsigned short* xhbf = (unsigned short*)(ws + 0);         // 8,388,608 us
    unsigned short* zbf  = (unsigned short*)(ws + 4194304);   // 8,388,608 us
    float* xdbl   = ws + 8388608;      // 327,680 f
    float* hx     = ws + 8716288;      // 4,194,304 f  hend -> hin in-place
    __half* dtvh  = (__half*)(ws + 12910592);                 // 8,388,608 h
    float* dtsg   = ws + 17104896;     // 262,144 f
    unsigned short* xcbf   = (unsigned short*)(ws + 17367040); // 8,388,608 us
    unsigned short* out_bf = (unsigned short*)(ws + 21561344); // 4,194,304 us
    float* part   = ws + 23658496;     // 64 f
    unsigned short* wtin  = (unsigned short*)(ws + 23658624); // 65,536 us
    unsigned short* wtout = (unsigned short*)(ws + 23691392); // 32,768 us
    unsigned short* ybf   = xhbf;      // alias: xhbf dead after k4
    float* outp   = (float*)d_out;

    k0_setup<<<25, 256, 0, stream>>>(W_in, W_out, wtin, wtout, part);
    k1_gemm_in<<<dim3(256, 2), 512, 0, stream>>>(x_hsi, wtin, xhbf, zbf);
    k4_xdbl<<<256, 256, 0, stream>>>(xhbf, conv_w, conv_b, W_x, xdbl, xcbf);
    k6_scan1<<<dim3(NCH, BATCH), 256, 0, stream>>>(xcbf, xdbl, W_dt, b_dt, A_log,
                                                   hx, dtsg, dtvh);
    k7_combine<<<128, 256, 0, stream>>>(dtsg, A_log, hx);
    k8_scan2<<<dim3(NCH, BATCH), 256, 0, stream>>>(xcbf, xdbl, dtvh,
                                                   A_log, Dv, hx, zbf, ybf);
    k9_gemm_out<<<256, 256, 0, stream>>>(ybf, wtout, out_bf, part);
    k10c_apply<<<4096, 256, 0, stream>>>(out_bf, part, gnw, gnb, x_hsi, outp);
}